// Round 4
// baseline (6742.028 us; speedup 1.0000x reference)
//
#include <hip/hip_runtime.h>
#include <hip/hip_bf16.h>

#define BB   256
#define TCAP 51
#define TT   50
#define VV   10000
#define WDIM 512
#define HH   512
#define ICC  2048
#define G3H  1536

#define TS 64
#define KS 16

// ---------------- sort (stable, descending by cap_lens) + tail outputs (float32!) ----------------
__global__ void sort_kernel(const int* __restrict__ cap_lens, const int* __restrict__ captions,
                            int* __restrict__ order_ws, int* __restrict__ len_ws,
                            int* __restrict__ caps_ws, float* __restrict__ out,
                            size_t predN) {
    __shared__ int s_order[BB];
    int i = threadIdx.x;
    int li = cap_lens[i];
    int rank = 0;
    for (int j = 0; j < BB; ++j) {
        int lj = cap_lens[j];
        rank += (lj > li) || (lj == li && j < i);
    }
    s_order[rank] = i;
    __syncthreads();
    int src = s_order[i];
    order_ws[i] = src;
    int len = cap_lens[src] - 1;
    len_ws[i] = len;
    for (int t = 0; t < TCAP; ++t) {
        int c = captions[src * TCAP + t];
        caps_ws[i * TCAP + t] = c;
        out[predN + (size_t)i * TCAP + t] = (float)c;
    }
    out[predN + (size_t)BB * TCAP + i]      = (float)len;
    out[predN + (size_t)BB * TCAP + BB + i] = (float)src;
}

// ---------------- gather image rows into sorted order ----------------
__global__ void gather_img(const float* __restrict__ image_code, const int* __restrict__ order_ws,
                           float* __restrict__ img_s) {
    int idx = blockIdx.x * blockDim.x + threadIdx.x;   // 256*2048 total
    int p = idx >> 11, c = idx & 2047;
    img_s[idx] = image_code[(size_t)order_ws[p] * ICC + c];
}

// ---------------- shared tiled f32 GEMM core: C_tile = A[s_arow] @ B^T ----------------
__device__ __forceinline__ void gemm_core(
    const float* __restrict__ A, int lda,
    const float* __restrict__ Bm, int ldb,
    const int* s_arow, int col0, int ncols, int K,
    float (*As)[TS + 1], float (*Bs)[TS + 1], float acc[4][4]) {
    const int tid = threadIdx.x;
    const int tx = tid & 15, ty = tid >> 4;
    for (int k0 = 0; k0 < K; k0 += KS) {
#pragma unroll
        for (int e = tid; e < TS * KS; e += 256) {
            int m = e >> 4, k = e & 15;
            As[k][m] = A[(size_t)s_arow[m] * lda + (k0 + k)];
            int bc = col0 + m;
            Bs[k][m] = (bc < ncols) ? Bm[(size_t)bc * ldb + (k0 + k)] : 0.f;
        }
        __syncthreads();
#pragma unroll
        for (int k = 0; k < KS; ++k) {
            float a0 = As[k][ty], a1 = As[k][ty + 16], a2 = As[k][ty + 32], a3 = As[k][ty + 48];
            float b0 = Bs[k][tx], b1 = Bs[k][tx + 16], b2 = Bs[k][tx + 32], b3 = Bs[k][tx + 48];
            acc[0][0] += a0 * b0; acc[0][1] += a0 * b1; acc[0][2] += a0 * b2; acc[0][3] += a0 * b3;
            acc[1][0] += a1 * b0; acc[1][1] += a1 * b1; acc[1][2] += a1 * b2; acc[1][3] += a1 * b3;
            acc[2][0] += a2 * b0; acc[2][1] += a2 * b1; acc[2][2] += a2 * b2; acc[2][3] += a2 * b3;
            acc[3][0] += a3 * b0; acc[3][1] += a3 * b1; acc[3][2] += a3 * b2; acc[3][3] += a3 * b3;
        }
        __syncthreads();
    }
}

// ---------------- h0 = img_s @ init_w^T + init_b  -> split into layer0/layer1 states ----------------
__global__ __launch_bounds__(256) void gemm_h0(const float* __restrict__ img_s,
                                               const float* __restrict__ init_w,
                                               const float* __restrict__ init_b,
                                               float* __restrict__ h0, float* __restrict__ h1) {
    __shared__ float As[KS][TS + 1], Bs[KS][TS + 1];
    __shared__ int s_arow[TS];
    int row0 = blockIdx.y * TS, col0 = blockIdx.x * TS;
    if (threadIdx.x < TS) s_arow[threadIdx.x] = row0 + threadIdx.x;
    __syncthreads();
    float acc[4][4] = {};
    gemm_core(img_s, ICC, init_w, ICC, s_arow, col0, 2 * HH, ICC, As, Bs, acc);
    int tx = threadIdx.x & 15, ty = threadIdx.x >> 4;
#pragma unroll
    for (int i = 0; i < 4; ++i)
#pragma unroll
        for (int j = 0; j < 4; ++j) {
            int r = row0 + ty + 16 * i, c = col0 + tx + 16 * j;
            float v = acc[i][j] + init_b[c];
            if (c < HH) h0[(size_t)r * HH + c] = v;
            else        h1[(size_t)r * HH + (c - HH)] = v;
        }
}

// ---------------- gi_img = img_s @ w_ih0[:, :IC]^T + b_ih0 ----------------
__global__ __launch_bounds__(256) void gemm_gi_img(const float* __restrict__ img_s,
                                                   const float* __restrict__ w_ih0,
                                                   const float* __restrict__ b_ih0,
                                                   float* __restrict__ gi_img) {
    __shared__ float As[KS][TS + 1], Bs[KS][TS + 1];
    __shared__ int s_arow[TS];
    int row0 = blockIdx.y * TS, col0 = blockIdx.x * TS;
    if (threadIdx.x < TS) s_arow[threadIdx.x] = row0 + threadIdx.x;
    __syncthreads();
    float acc[4][4] = {};
    gemm_core(img_s, ICC, w_ih0, ICC + WDIM, s_arow, col0, G3H, ICC, As, Bs, acc);
    int tx = threadIdx.x & 15, ty = threadIdx.x >> 4;
#pragma unroll
    for (int i = 0; i < 4; ++i)
#pragma unroll
        for (int j = 0; j < 4; ++j) {
            int r = row0 + ty + 16 * i, c = col0 + tx + 16 * j;
            gi_img[(size_t)r * G3H + c] = acc[i][j] + b_ih0[c];
        }
}

// ---------------- gi_all[t,p,:] = emb(caps[p,t]) @ w_ih0[:, IC:]^T + gi_img[p,:] ----------------
__global__ __launch_bounds__(256) void gemm_gi_emb(const float* __restrict__ embed_w,
                                                   const float* __restrict__ w_ih0,
                                                   const float* __restrict__ gi_img,
                                                   const int* __restrict__ caps_ws,
                                                   const int* __restrict__ len_ws,
                                                   float* __restrict__ gi_all) {
    int r0 = blockIdx.y * TS;
    int t = r0 >> 8, p0 = r0 & 255;
    if (len_ws[p0] <= t) return;   // whole tile past length; gi never observed
    __shared__ float As[KS][TS + 1], Bs[KS][TS + 1];
    __shared__ int s_arow[TS];
    if (threadIdx.x < TS) s_arow[threadIdx.x] = caps_ws[(p0 + threadIdx.x) * TCAP + t];
    __syncthreads();
    int col0 = blockIdx.x * TS;
    float acc[4][4] = {};
    gemm_core(embed_w, WDIM, w_ih0 + ICC, ICC + WDIM, s_arow, col0, G3H, WDIM, As, Bs, acc);
    int tx = threadIdx.x & 15, ty = threadIdx.x >> 4;
#pragma unroll
    for (int i = 0; i < 4; ++i)
#pragma unroll
        for (int j = 0; j < 4; ++j) {
            int p = p0 + ty + 16 * i, c = col0 + tx + 16 * j;
            gi_all[((size_t)t * BB + p) * G3H + c] = acc[i][j] + gi_img[(size_t)p * G3H + c];
        }
}

// ---------------- predictions = H1_all @ fc_w^T + fc_b, masked, float32 store ----------------
__global__ __launch_bounds__(256) void gemm_fc(const float* __restrict__ h1_all,
                                               const float* __restrict__ fc_w,
                                               const float* __restrict__ fc_b,
                                               const int* __restrict__ len_ws,
                                               float* __restrict__ out) {
    int r0 = blockIdx.y * TS;
    int t = r0 >> 8, p0 = r0 & 255;
    int col0 = blockIdx.x * TS;
    if (len_ws[p0] <= t) {          // fully masked tile -> zeros
        for (int e = threadIdx.x; e < TS * TS; e += 256) {
            int rl = e >> 6, cl = e & 63;
            int c = col0 + cl;
            if (c < VV) out[((size_t)(p0 + rl) * TT + t) * VV + c] = 0.f;
        }
        return;
    }
    __shared__ float As[KS][TS + 1], Bs[KS][TS + 1];
    __shared__ int s_arow[TS];
    if (threadIdx.x < TS) s_arow[threadIdx.x] = r0 + threadIdx.x;
    __syncthreads();
    float acc[4][4] = {};
    gemm_core(h1_all, HH, fc_w, HH, s_arow, col0, VV, HH, As, Bs, acc);
    int tx = threadIdx.x & 15, ty = threadIdx.x >> 4;
#pragma unroll
    for (int i = 0; i < 4; ++i)
#pragma unroll
        for (int j = 0; j < 4; ++j) {
            int p = p0 + ty + 16 * i, c = col0 + tx + 16 * j;
            if (c < VV) {
                bool act = (t < len_ws[p]);
                float v = act ? (acc[i][j] + fc_b[c]) : 0.f;
                out[((size_t)p * TT + t) * VV + c] = v;
            }
        }
}

// ---------------- GRU step: one layer, no cross-block deps (double-buffered h) ----------------
// 8 rows x 64 cols per block: dynamic LDS = 8*HPAD*4 (L0) / 16*HPAD*4 (L1) bytes,
// both under the 64 KiB per-block dynamic-LDS limit.
__device__ __forceinline__ float dot4(float4 a, float4 b) {
    return a.x * b.x + a.y * b.y + a.z * b.z + a.w * b.w;
}

#define HPAD 516   // 512 + 4 pad: breaks LDS bank aliasing for row-strided reads

template <int LAYER>
__global__ __launch_bounds__(256) void gru_step(int t,
    const float* __restrict__ gi_all,   // LAYER==0: precomputed x-gates (incl. b_ih0)
    const float* __restrict__ x_in,     // LAYER==1: h0_new of this step
    const float* __restrict__ h_in,     // previous hidden of this layer
    float* __restrict__ h_out,          // next hidden buffer of this layer
    float* __restrict__ h1_all,         // LAYER==1: store h1 state for fc
    const float* __restrict__ w_hh, const float* __restrict__ b_hh,
    const float* __restrict__ w_ih, const float* __restrict__ b_ih,
    const int* __restrict__ len_ws) {
    const int c0 = blockIdx.x * 64;    // 8 col-blocks cover 512 cols
    const int p0 = blockIdx.y * 8;     // 32 row-blocks cover 256 rows
    if (len_ws[p0] <= t) return;   // whole row-tile inactive: old h preserved (never read again)
    extern __shared__ float smem[];
    float* s_h = smem;
    float* s_x = smem + 8 * HPAD;
    for (int e = threadIdx.x; e < 8 * HH; e += 256) {
        int rw = e >> 9, k = e & 511;
        s_h[rw * HPAD + k] = h_in[(size_t)(p0 + rw) * HH + k];
        if (LAYER) s_x[rw * HPAD + k] = x_in[(size_t)(p0 + rw) * HH + k];
    }
    __syncthreads();
    const int rl = threadIdx.x & 7;    // row within tile (0..7)
    const int cp = threadIdx.x >> 3;   // col-pair index (0..31)
    const int c = c0 + cp * 2;
    float ar0 = 0, ar1 = 0, az0 = 0, az1 = 0, an0 = 0, an1 = 0;
    float xr0 = 0, xr1 = 0, xz0 = 0, xz1 = 0, xn0 = 0, xn1 = 0;
    const float4* hp  = (const float4*)(s_h + rl * HPAD);
    const float4* xp  = (const float4*)(s_x + rl * HPAD);
    const float4* whr = (const float4*)(w_hh + (size_t)c * HH);
    const float4* whz = (const float4*)(w_hh + (size_t)(HH + c) * HH);
    const float4* whn = (const float4*)(w_hh + (size_t)(2 * HH + c) * HH);
    const float4* wir = (const float4*)(w_ih + (size_t)c * HH);
    const float4* wiz = (const float4*)(w_ih + (size_t)(HH + c) * HH);
    const float4* win = (const float4*)(w_ih + (size_t)(2 * HH + c) * HH);
    for (int k4 = 0; k4 < HH / 4; ++k4) {
        float4 h = hp[k4];
        ar0 += dot4(h, whr[k4]); ar1 += dot4(h, whr[k4 + 128]);
        az0 += dot4(h, whz[k4]); az1 += dot4(h, whz[k4 + 128]);
        an0 += dot4(h, whn[k4]); an1 += dot4(h, whn[k4 + 128]);
        if (LAYER) {
            float4 x = xp[k4];
            xr0 += dot4(x, wir[k4]); xr1 += dot4(x, wir[k4 + 128]);
            xz0 += dot4(x, wiz[k4]); xz1 += dot4(x, wiz[k4 + 128]);
            xn0 += dot4(x, win[k4]); xn1 += dot4(x, win[k4 + 128]);
        }
    }
    const int p = p0 + rl;
    if (t >= len_ws[p]) return;   // inactive row: preserve (stale is unobservable)
#pragma unroll
    for (int u = 0; u < 2; ++u) {
        int cc = c + u;
        float gr, gz, gn;
        if (LAYER == 0) {
            const float* gi = gi_all + ((size_t)t * BB + p) * G3H;
            gr = gi[cc]; gz = gi[HH + cc]; gn = gi[2 * HH + cc];
        } else {
            gr = (u ? xr1 : xr0) + b_ih[cc];
            gz = (u ? xz1 : xz0) + b_ih[HH + cc];
            gn = (u ? xn1 : xn0) + b_ih[2 * HH + cc];
        }
        float hr = (u ? ar1 : ar0) + b_hh[cc];
        float hz = (u ? az1 : az0) + b_hh[HH + cc];
        float hn = (u ? an1 : an0) + b_hh[2 * HH + cc];
        float r = 1.f / (1.f + expf(-(gr + hr)));
        float z = 1.f / (1.f + expf(-(gz + hz)));
        float n = tanhf(gn + r * hn);
        float hold = s_h[rl * HPAD + cc];
        float hnew = (1.f - z) * n + z * hold;
        h_out[(size_t)p * HH + cc] = hnew;
        if (LAYER) h1_all[((size_t)t * BB + p) * HH + cc] = hnew;
    }
}

// ---------------- launch ----------------
extern "C" void kernel_launch(void* const* d_in, const int* in_sizes, int n_in,
                              void* d_out, int out_size, void* d_ws, size_t ws_size,
                              hipStream_t stream) {
    const float* image_code = (const float*)d_in[0];
    const int*   captions   = (const int*)d_in[1];
    const int*   cap_lens   = (const int*)d_in[2];
    const float* embed_w    = (const float*)d_in[3];
    const float* init_w     = (const float*)d_in[4];
    const float* init_b     = (const float*)d_in[5];
    const float* w_ih0      = (const float*)d_in[6];
    const float* w_hh0      = (const float*)d_in[7];
    const float* b_ih0      = (const float*)d_in[8];
    const float* b_hh0      = (const float*)d_in[9];
    const float* w_ih1      = (const float*)d_in[10];
    const float* w_hh1      = (const float*)d_in[11];
    const float* b_ih1      = (const float*)d_in[12];
    const float* b_hh1      = (const float*)d_in[13];
    const float* fc_w       = (const float*)d_in[14];
    const float* fc_b       = (const float*)d_in[15];
    float* out = (float*)d_out;   // float32: reference output dtype (predictions f32)

    // Output layout (float elements): predictions | caps(BB*TCAP) | lengths(BB) | order(BB)
    const size_t tail = (size_t)BB * TCAP + 2 * BB;            // 13,568
    const size_t predN = (size_t)out_size - tail;              // = BB*TT*VV = 128,000,000

    char* ws = (char*)d_ws;
    int*   order_ws = (int*)(ws + 0);
    int*   len_ws   = (int*)(ws + 1024);
    int*   caps_ws  = (int*)(ws + 2048);
    float* img_s    = (float*)(ws + 54272);
    float* h0a      = (float*)(ws + 2151424);
    float* h0b      = (float*)(ws + 2675712);
    float* h1a      = (float*)(ws + 3200000);
    float* h1b      = (float*)(ws + 3724288);
    float* gi_img   = (float*)(ws + 4248576);
    float* gi_all   = (float*)(ws + 5821440);
    float* h1_all   = (float*)(ws + 84464640);

    dim3 blk(256);
    hipLaunchKernelGGL(sort_kernel, dim3(1), blk, 0, stream,
                       cap_lens, captions, order_ws, len_ws, caps_ws, out, predN);
    hipLaunchKernelGGL(gather_img, dim3(2048), blk, 0, stream, image_code, order_ws, img_s);
    hipLaunchKernelGGL(gemm_h0, dim3(16, 4), blk, 0, stream, img_s, init_w, init_b, h0a, h1a);
    hipLaunchKernelGGL(gemm_gi_img, dim3(24, 4), blk, 0, stream, img_s, w_ih0, b_ih0, gi_img);
    hipLaunchKernelGGL(gemm_gi_emb, dim3(24, 200), blk, 0, stream,
                       embed_w, w_ih0, gi_img, caps_ws, len_ws, gi_all);
    for (int t = 0; t < TT; ++t) {
        int cur = t & 1;
        float* h0c = cur ? h0b : h0a; float* h0n = cur ? h0a : h0b;
        float* h1c = cur ? h1b : h1a; float* h1n = cur ? h1a : h1b;
        gru_step<0><<<dim3(8, 32), blk, 8 * HPAD * 4, stream>>>(
            t, gi_all, nullptr, h0c, h0n, nullptr, w_hh0, b_hh0, nullptr, nullptr, len_ws);
        gru_step<1><<<dim3(8, 32), blk, 16 * HPAD * 4, stream>>>(
            t, nullptr, h0n, h1c, h1n, h1_all, w_hh1, b_hh1, w_ih1, b_ih1, len_ws);
    }
    hipLaunchKernelGGL(gemm_fc, dim3(157, 200), blk, 0, stream, h1_all, fc_w, fc_b, len_ws, out);
}

// Round 5
// 5214.142 us; speedup vs baseline: 1.2930x; 1.2930x over previous
//
#include <hip/hip_runtime.h>
#include <hip/hip_bf16.h>

#define BB   256
#define TCAP 51
#define TT   50
#define VV   10000
#define WDIM 512
#define HH   512
#define ICC  2048
#define G3H  1536

#define TS 64
#define KS 16

typedef __attribute__((ext_vector_type(8))) short short8v;
typedef __attribute__((ext_vector_type(4))) float f32x4;

__device__ __forceinline__ unsigned short f2bf(float f) {
    unsigned u; __builtin_memcpy(&u, &f, 4);
    unsigned r = (u + 0x7FFFu + ((u >> 16) & 1u)) >> 16;   // RNE
    return (unsigned short)r;
}

// ---------------- sort (stable, descending by cap_lens) + tail outputs (float32) ----------------
__global__ void sort_kernel(const int* __restrict__ cap_lens, const int* __restrict__ captions,
                            int* __restrict__ order_ws, int* __restrict__ len_ws,
                            int* __restrict__ caps_ws, float* __restrict__ out,
                            size_t predN) {
    __shared__ int s_order[BB];
    int i = threadIdx.x;
    int li = cap_lens[i];
    int rank = 0;
    for (int j = 0; j < BB; ++j) {
        int lj = cap_lens[j];
        rank += (lj > li) || (lj == li && j < i);
    }
    s_order[rank] = i;
    __syncthreads();
    int src = s_order[i];
    order_ws[i] = src;
    int len = cap_lens[src] - 1;
    len_ws[i] = len;
    for (int t = 0; t < TCAP; ++t) {
        int c = captions[src * TCAP + t];
        caps_ws[i * TCAP + t] = c;
        out[predN + (size_t)i * TCAP + t] = (float)c;
    }
    out[predN + (size_t)BB * TCAP + i]      = (float)len;
    out[predN + (size_t)BB * TCAP + BB + i] = (float)src;
}

// ---------------- gather image rows into sorted order ----------------
__global__ void gather_img(const float* __restrict__ image_code, const int* __restrict__ order_ws,
                           float* __restrict__ img_s) {
    int idx = blockIdx.x * blockDim.x + threadIdx.x;   // 256*2048 total
    int p = idx >> 11, c = idx & 2047;
    img_s[idx] = image_code[(size_t)order_ws[p] * ICC + c];
}

// ---------------- fc_w f32 -> bf16 ----------------
__global__ void wcvt(const float* __restrict__ src, unsigned short* __restrict__ dst, int n4) {
    int i = blockIdx.x * blockDim.x + threadIdx.x;
    if (i < n4) {
        float4 v = ((const float4*)src)[i];
        ushort4 o;
        o.x = f2bf(v.x); o.y = f2bf(v.y); o.z = f2bf(v.z); o.w = f2bf(v.w);
        ((ushort4*)dst)[i] = o;
    }
}

// ---------------- shared tiled f32 GEMM core: C_tile = A[s_arow] @ B^T ----------------
__device__ __forceinline__ void gemm_core(
    const float* __restrict__ A, int lda,
    const float* __restrict__ Bm, int ldb,
    const int* s_arow, int col0, int ncols, int K,
    float (*As)[TS + 1], float (*Bs)[TS + 1], float acc[4][4]) {
    const int tid = threadIdx.x;
    const int tx = tid & 15, ty = tid >> 4;
    for (int k0 = 0; k0 < K; k0 += KS) {
#pragma unroll
        for (int e = tid; e < TS * KS; e += 256) {
            int m = e >> 4, k = e & 15;
            As[k][m] = A[(size_t)s_arow[m] * lda + (k0 + k)];
            int bc = col0 + m;
            Bs[k][m] = (bc < ncols) ? Bm[(size_t)bc * ldb + (k0 + k)] : 0.f;
        }
        __syncthreads();
#pragma unroll
        for (int k = 0; k < KS; ++k) {
            float a0 = As[k][ty], a1 = As[k][ty + 16], a2 = As[k][ty + 32], a3 = As[k][ty + 48];
            float b0 = Bs[k][tx], b1 = Bs[k][tx + 16], b2 = Bs[k][tx + 32], b3 = Bs[k][tx + 48];
            acc[0][0] += a0 * b0; acc[0][1] += a0 * b1; acc[0][2] += a0 * b2; acc[0][3] += a0 * b3;
            acc[1][0] += a1 * b0; acc[1][1] += a1 * b1; acc[1][2] += a1 * b2; acc[1][3] += a1 * b3;
            acc[2][0] += a2 * b0; acc[2][1] += a2 * b1; acc[2][2] += a2 * b2; acc[2][3] += a2 * b3;
            acc[3][0] += a3 * b0; acc[3][1] += a3 * b1; acc[3][2] += a3 * b2; acc[3][3] += a3 * b3;
        }
        __syncthreads();
    }
}

// ---------------- h0 = img_s @ init_w^T + init_b  -> split into layer0/layer1 states ----------------
__global__ __launch_bounds__(256) void gemm_h0(const float* __restrict__ img_s,
                                               const float* __restrict__ init_w,
                                               const float* __restrict__ init_b,
                                               float* __restrict__ h0, float* __restrict__ h1) {
    __shared__ float As[KS][TS + 1], Bs[KS][TS + 1];
    __shared__ int s_arow[TS];
    int row0 = blockIdx.y * TS, col0 = blockIdx.x * TS;
    if (threadIdx.x < TS) s_arow[threadIdx.x] = row0 + threadIdx.x;
    __syncthreads();
    float acc[4][4] = {};
    gemm_core(img_s, ICC, init_w, ICC, s_arow, col0, 2 * HH, ICC, As, Bs, acc);
    int tx = threadIdx.x & 15, ty = threadIdx.x >> 4;
#pragma unroll
    for (int i = 0; i < 4; ++i)
#pragma unroll
        for (int j = 0; j < 4; ++j) {
            int r = row0 + ty + 16 * i, c = col0 + tx + 16 * j;
            float v = acc[i][j] + init_b[c];
            if (c < HH) h0[(size_t)r * HH + c] = v;
            else        h1[(size_t)r * HH + (c - HH)] = v;
        }
}

// ---------------- gi_img = img_s @ w_ih0[:, :IC]^T + b_ih0 ----------------
__global__ __launch_bounds__(256) void gemm_gi_img(const float* __restrict__ img_s,
                                                   const float* __restrict__ w_ih0,
                                                   const float* __restrict__ b_ih0,
                                                   float* __restrict__ gi_img) {
    __shared__ float As[KS][TS + 1], Bs[KS][TS + 1];
    __shared__ int s_arow[TS];
    int row0 = blockIdx.y * TS, col0 = blockIdx.x * TS;
    if (threadIdx.x < TS) s_arow[threadIdx.x] = row0 + threadIdx.x;
    __syncthreads();
    float acc[4][4] = {};
    gemm_core(img_s, ICC, w_ih0, ICC + WDIM, s_arow, col0, G3H, ICC, As, Bs, acc);
    int tx = threadIdx.x & 15, ty = threadIdx.x >> 4;
#pragma unroll
    for (int i = 0; i < 4; ++i)
#pragma unroll
        for (int j = 0; j < 4; ++j) {
            int r = row0 + ty + 16 * i, c = col0 + tx + 16 * j;
            gi_img[(size_t)r * G3H + c] = acc[i][j] + b_ih0[c];
        }
}

// ---------------- gi_all[t,p,:] = emb(caps[p,t]) @ w_ih0[:, IC:]^T + gi_img[p,:] ----------------
__global__ __launch_bounds__(256) void gemm_gi_emb(const float* __restrict__ embed_w,
                                                   const float* __restrict__ w_ih0,
                                                   const float* __restrict__ gi_img,
                                                   const int* __restrict__ caps_ws,
                                                   const int* __restrict__ len_ws,
                                                   float* __restrict__ gi_all) {
    int r0 = blockIdx.y * TS;
    int t = r0 >> 8, p0 = r0 & 255;
    if (len_ws[p0] <= t) return;   // whole tile past length; gi never observed
    __shared__ float As[KS][TS + 1], Bs[KS][TS + 1];
    __shared__ int s_arow[TS];
    if (threadIdx.x < TS) s_arow[threadIdx.x] = caps_ws[(p0 + threadIdx.x) * TCAP + t];
    __syncthreads();
    int col0 = blockIdx.x * TS;
    float acc[4][4] = {};
    gemm_core(embed_w, WDIM, w_ih0 + ICC, ICC + WDIM, s_arow, col0, G3H, WDIM, As, Bs, acc);
    int tx = threadIdx.x & 15, ty = threadIdx.x >> 4;
#pragma unroll
    for (int i = 0; i < 4; ++i)
#pragma unroll
        for (int j = 0; j < 4; ++j) {
            int p = p0 + ty + 16 * i, c = col0 + tx + 16 * j;
            gi_all[((size_t)t * BB + p) * G3H + c] = acc[i][j] + gi_img[(size_t)p * G3H + c];
        }
}

// ---------------- predictions = H1_all(bf16) @ fc_wb^T + fc_b via MFMA, masked, f32 store ----------
#define FCP 8
__global__ __launch_bounds__(256) void gemm_fc_mfma(
    const unsigned short* __restrict__ h1x,   // [TT*BB][512] bf16 bits (t-major rows)
    const unsigned short* __restrict__ fcwb,  // [VV][512] bf16 bits
    const float* __restrict__ fc_b,
    const int* __restrict__ len_ws,
    float* __restrict__ out) {
    const int r0 = blockIdx.y * 64;           // rows within 12800 = t*256 + p
    const int t = r0 >> 8, p0 = r0 & 255;
    const int c0 = blockIdx.x * 64;
    const int tid = threadIdx.x;
    if (len_ws[p0] <= t) {                    // fully masked row tile -> zeros
        for (int e = tid; e < 64 * 16; e += 256) {
            int rl = e >> 4, c = c0 + (e & 15) * 4;
            if (c < VV) {
                float4 z = {0.f, 0.f, 0.f, 0.f};
                *(float4*)&out[((size_t)(p0 + rl) * TT + t) * VV + c] = z;
            }
        }
        return;
    }
    __shared__ unsigned short As[64][64 + FCP];
    __shared__ unsigned short Bs[64][64 + FCP];
    const int lane = tid & 63, w = tid >> 6;
    f32x4 acc[4] = {};
    for (int k0 = 0; k0 < HH; k0 += 64) {
#pragma unroll
        for (int v = 0; v < 2; ++v) {
            int e = tid + v * 256;            // 0..511
            int rr = e >> 3, kk = (e & 7) * 8;
            *(short8v*)&As[rr][kk] =
                *(const short8v*)&h1x[((size_t)(t * BB + p0 + rr)) * HH + k0 + kk];
            int bc = c0 + rr;
            short8v bv = {};
            if (bc < VV) bv = *(const short8v*)&fcwb[(size_t)bc * HH + k0 + kk];
            *(short8v*)&Bs[rr][kk] = bv;
        }
        __syncthreads();
#pragma unroll
        for (int ks = 0; ks < 64; ks += 32) {
            short8v a = *(const short8v*)&As[w * 16 + (lane & 15)][ks + (lane >> 4) * 8];
#pragma unroll
            for (int n = 0; n < 4; ++n) {
                short8v b = *(const short8v*)&Bs[n * 16 + (lane & 15)][ks + (lane >> 4) * 8];
                acc[n] = __builtin_amdgcn_mfma_f32_16x16x32_bf16(a, b, acc[n], 0, 0, 0);
            }
        }
        __syncthreads();
    }
    // C/D layout: col = lane&15, row = (lane>>4)*4 + reg   [verified mapping]
#pragma unroll
    for (int n = 0; n < 4; ++n) {
        int c = c0 + n * 16 + (lane & 15);
        if (c < VV) {
            float bias = fc_b[c];
#pragma unroll
            for (int r = 0; r < 4; ++r) {
                int pr = p0 + w * 16 + (lane >> 4) * 4 + r;
                bool act = (t < len_ws[pr]);
                out[((size_t)pr * TT + t) * VV + c] = act ? (acc[n][r] + bias) : 0.f;
            }
        }
    }
}

// ---------------- GRU step: 128 thr, 8 rows x 32 cols per block, 512 blocks ----------------
__device__ __forceinline__ float dot4(float4 a, float4 b) {
    return a.x * b.x + a.y * b.y + a.z * b.z + a.w * b.w;
}

#define HPAD 516   // 512 + 4 pad

template <int LAYER>
__global__ __launch_bounds__(128) void gru_step(int t,
    const float* __restrict__ gi_all,   // LAYER==0: precomputed x-gates (incl. b_ih0)
    const float* __restrict__ x_in,     // LAYER==1: h0_new of this step
    const float* __restrict__ h_in,     // previous hidden of this layer
    float* __restrict__ h_out,          // next hidden buffer of this layer
    unsigned short* __restrict__ h1x,   // LAYER==1: bf16 h1 state for fc
    const float* __restrict__ w_hh, const float* __restrict__ b_hh,
    const float* __restrict__ w_ih, const float* __restrict__ b_ih,
    const int* __restrict__ len_ws) {
    const int c0 = blockIdx.x * 32;    // 16 col-blocks cover 512 cols
    const int p0 = blockIdx.y * 8;     // 32 row-blocks cover 256 rows
    if (len_ws[p0] <= t) return;       // inactive tile: stale h never observed
    extern __shared__ float smem[];
    float* s_h = smem;
    float* s_x = smem + 8 * HPAD;
    for (int e = threadIdx.x; e < 8 * HH; e += 128) {
        int rw = e >> 9, k = e & 511;
        s_h[rw * HPAD + k] = h_in[(size_t)(p0 + rw) * HH + k];
        if (LAYER) s_x[rw * HPAD + k] = x_in[(size_t)(p0 + rw) * HH + k];
    }
    __syncthreads();
    const int rl = threadIdx.x & 7;    // row (0..7)
    const int cp = threadIdx.x >> 3;   // col-pair (0..15)
    const int c = c0 + cp * 2;
    float ar0 = 0, ar1 = 0, az0 = 0, az1 = 0, an0 = 0, an1 = 0;
    float xr0 = 0, xr1 = 0, xz0 = 0, xz1 = 0, xn0 = 0, xn1 = 0;
    const float4* hp  = (const float4*)(s_h + rl * HPAD);
    const float4* xp  = (const float4*)(s_x + rl * HPAD);
    const float4* whr = (const float4*)(w_hh + (size_t)c * HH);
    const float4* whz = (const float4*)(w_hh + (size_t)(HH + c) * HH);
    const float4* whn = (const float4*)(w_hh + (size_t)(2 * HH + c) * HH);
    const float4* wir = (const float4*)(w_ih + (size_t)c * HH);
    const float4* wiz = (const float4*)(w_ih + (size_t)(HH + c) * HH);
    const float4* win = (const float4*)(w_ih + (size_t)(2 * HH + c) * HH);
    for (int k4 = 0; k4 < HH / 4; ++k4) {
        float4 h = hp[k4];
        ar0 += dot4(h, whr[k4]); ar1 += dot4(h, whr[k4 + 128]);
        az0 += dot4(h, whz[k4]); az1 += dot4(h, whz[k4 + 128]);
        an0 += dot4(h, whn[k4]); an1 += dot4(h, whn[k4 + 128]);
        if (LAYER) {
            float4 x = xp[k4];
            xr0 += dot4(x, wir[k4]); xr1 += dot4(x, wir[k4 + 128]);
            xz0 += dot4(x, wiz[k4]); xz1 += dot4(x, wiz[k4 + 128]);
            xn0 += dot4(x, win[k4]); xn1 += dot4(x, win[k4 + 128]);
        }
    }
    const int p = p0 + rl;
    if (t >= len_ws[p]) return;        // inactive row: preserve (stale unobservable)
#pragma unroll
    for (int u = 0; u < 2; ++u) {
        int cc = c + u;
        float gr, gz, gn;
        if (LAYER == 0) {
            const float* gi = gi_all + ((size_t)t * BB + p) * G3H;
            gr = gi[cc]; gz = gi[HH + cc]; gn = gi[2 * HH + cc];
        } else {
            gr = (u ? xr1 : xr0) + b_ih[cc];
            gz = (u ? xz1 : xz0) + b_ih[HH + cc];
            gn = (u ? xn1 : xn0) + b_ih[2 * HH + cc];
        }
        float hr = (u ? ar1 : ar0) + b_hh[cc];
        float hz = (u ? az1 : az0) + b_hh[HH + cc];
        float hn = (u ? an1 : an0) + b_hh[2 * HH + cc];
        float r = 1.f / (1.f + expf(-(gr + hr)));
        float z = 1.f / (1.f + expf(-(gz + hz)));
        float n = tanhf(gn + r * hn);
        float hold = s_h[rl * HPAD + cc];
        float hnew = (1.f - z) * n + z * hold;
        h_out[(size_t)p * HH + cc] = hnew;
        if (LAYER) h1x[((size_t)t * BB + p) * HH + cc] = f2bf(hnew);
    }
}

// ---------------- launch ----------------
extern "C" void kernel_launch(void* const* d_in, const int* in_sizes, int n_in,
                              void* d_out, int out_size, void* d_ws, size_t ws_size,
                              hipStream_t stream) {
    const float* image_code = (const float*)d_in[0];
    const int*   captions   = (const int*)d_in[1];
    const int*   cap_lens   = (const int*)d_in[2];
    const float* embed_w    = (const float*)d_in[3];
    const float* init_w     = (const float*)d_in[4];
    const float* init_b     = (const float*)d_in[5];
    const float* w_ih0      = (const float*)d_in[6];
    const float* w_hh0      = (const float*)d_in[7];
    const float* b_ih0      = (const float*)d_in[8];
    const float* b_hh0      = (const float*)d_in[9];
    const float* w_ih1      = (const float*)d_in[10];
    const float* w_hh1      = (const float*)d_in[11];
    const float* b_ih1      = (const float*)d_in[12];
    const float* b_hh1      = (const float*)d_in[13];
    const float* fc_w       = (const float*)d_in[14];
    const float* fc_b       = (const float*)d_in[15];
    float* out = (float*)d_out;   // float32 (reference output dtype)

    const size_t tail = (size_t)BB * TCAP + 2 * BB;            // 13,568
    const size_t predN = (size_t)out_size - tail;              // BB*TT*VV

    char* ws = (char*)d_ws;
    int*   order_ws = (int*)(ws + 0);
    int*   len_ws   = (int*)(ws + 1024);
    int*   caps_ws  = (int*)(ws + 2048);
    float* img_s    = (float*)(ws + 54272);
    float* h0a      = (float*)(ws + 2151424);
    float* h0b      = (float*)(ws + 2675712);
    float* h1a      = (float*)(ws + 3200000);
    float* h1b      = (float*)(ws + 3724288);
    float* gi_img   = (float*)(ws + 4248576);
    float* gi_all   = (float*)(ws + 5821440);
    unsigned short* h1x  = (unsigned short*)(ws + 84464640);   // TT*BB*HH bf16 = 13,107,200 B
    unsigned short* fcwb = (unsigned short*)(ws + 97571840);   // VV*HH bf16    = 10,240,000 B

    dim3 blk(256);
    hipLaunchKernelGGL(sort_kernel, dim3(1), blk, 0, stream,
                       cap_lens, captions, order_ws, len_ws, caps_ws, out, predN);
    hipLaunchKernelGGL(gather_img, dim3(2048), blk, 0, stream, image_code, order_ws, img_s);
    hipLaunchKernelGGL(wcvt, dim3((VV * HH / 4 + 255) / 256), blk, 0, stream,
                       fc_w, fcwb, VV * HH / 4);
    hipLaunchKernelGGL(gemm_h0, dim3(16, 4), blk, 0, stream, img_s, init_w, init_b, h0a, h1a);
    hipLaunchKernelGGL(gemm_gi_img, dim3(24, 4), blk, 0, stream, img_s, w_ih0, b_ih0, gi_img);
    hipLaunchKernelGGL(gemm_gi_emb, dim3(24, 200), blk, 0, stream,
                       embed_w, w_ih0, gi_img, caps_ws, len_ws, gi_all);
    for (int t = 0; t < TT; ++t) {
        int cur = t & 1;
        float* h0c = cur ? h0b : h0a; float* h0n = cur ? h0a : h0b;
        float* h1c = cur ? h1b : h1a; float* h1n = cur ? h1a : h1b;
        gru_step<0><<<dim3(16, 32), dim3(128), 8 * HPAD * 4, stream>>>(
            t, gi_all, nullptr, h0c, h0n, nullptr, w_hh0, b_hh0, nullptr, nullptr, len_ws);
        gru_step<1><<<dim3(16, 32), dim3(128), 16 * HPAD * 4, stream>>>(
            t, nullptr, h0n, h1c, h1n, h1x, w_hh1, b_hh1, w_ih1, b_ih1, len_ws);
    }
    hipLaunchKernelGGL(gemm_fc_mfma, dim3(157, 200), blk, 0, stream,
                       h1x, fcwb, fc_b, len_ws, out);
}